// Round 3
// baseline (701.614 us; speedup 1.0000x reference)
//
#include <hip/hip_runtime.h>
#include <hip/hip_bf16.h>

#define BB 32768
#define AA 64
#define HH 1024
#define DD 256
#define KK 4096

typedef __hip_bfloat16 bf16;
typedef __attribute__((ext_vector_type(8))) short bf16x8;
typedef __attribute__((ext_vector_type(4))) float f32x4;
typedef unsigned long long u64;

__device__ __forceinline__ float b2f(bf16 x) { return __bfloat162float(x); }
__device__ __forceinline__ bf16 f2b(float x) { return __float2bfloat16(x); }
__device__ __forceinline__ unsigned f2ord(float f) {
    unsigned u = __float_as_uint(f);
    return (u & 0x80000000u) ? ~u : (u | 0x80000000u);
}

// ---------------------------------------------------------------------------
// Prep: convert action to bf16; convert+transpose all weights to bf16 [N,K];
// codebook bf16 (already [N,K]); codebook row norms.
// ---------------------------------------------------------------------------
__global__ void prep_kernel(const float* __restrict__ action,
                            const float* __restrict__ enc_w1,
                            const float* __restrict__ enc_w2,
                            const float* __restrict__ mu_w,
                            const float* __restrict__ codebook,
                            const float* __restrict__ dec_w1,
                            const float* __restrict__ dec_w2,
                            const float* __restrict__ dec_w3,
                            bf16* __restrict__ action_bf, bf16* __restrict__ ew1t,
                            bf16* __restrict__ ew2t, bf16* __restrict__ muwt,
                            bf16* __restrict__ cbb, bf16* __restrict__ dw1t,
                            bf16* __restrict__ dw2t, bf16* __restrict__ dw3t,
                            float* __restrict__ cnorm)
{
    int blk = blockIdx.x;
    const int t = threadIdx.x;
    if (blk < 2048) {
        int base = blk * 1024 + t;
#pragma unroll
        for (int i = 0; i < 4; i++) { int e = base + i * 256; action_bf[e] = f2b(action[e]); }
        return;
    }
    blk -= 2048;
    if (blk < 64) {  // enc_w1 (64,1024) -> [1024,64]
        int base = blk * 1024 + t;
#pragma unroll
        for (int i = 0; i < 4; i++) { int e = base + i * 256; int n = e >> 6, k = e & 63;
            ew1t[e] = f2b(enc_w1[k * HH + n]); }
        return;
    }
    blk -= 64;
    if (blk < 1024) {  // enc_w2 (1024,1024) -> T
        int base = blk * 1024 + t;
#pragma unroll
        for (int i = 0; i < 4; i++) { int e = base + i * 256; int n = e >> 10, k = e & 1023;
            ew2t[e] = f2b(enc_w2[k * HH + n]); }
        return;
    }
    blk -= 1024;
    if (blk < 256) {  // mu_w (1024,256) -> [256,1024]
        int base = blk * 1024 + t;
#pragma unroll
        for (int i = 0; i < 4; i++) { int e = base + i * 256; int n = e >> 10, k = e & 1023;
            muwt[e] = f2b(mu_w[k * DD + n]); }
        return;
    }
    blk -= 256;
    if (blk < 1024) {  // codebook convert (no transpose)
        int base = blk * 1024 + t;
#pragma unroll
        for (int i = 0; i < 4; i++) { int e = base + i * 256; cbb[e] = f2b(codebook[e]); }
        return;
    }
    blk -= 1024;
    if (blk < 256) {  // dec_w1 (256,1024) -> [1024,256]
        int base = blk * 1024 + t;
#pragma unroll
        for (int i = 0; i < 4; i++) { int e = base + i * 256; int n = e >> 8, k = e & 255;
            dw1t[e] = f2b(dec_w1[k * HH + n]); }
        return;
    }
    blk -= 256;
    if (blk < 1024) {  // dec_w2 (1024,1024) -> T
        int base = blk * 1024 + t;
#pragma unroll
        for (int i = 0; i < 4; i++) { int e = base + i * 256; int n = e >> 10, k = e & 1023;
            dw2t[e] = f2b(dec_w2[k * HH + n]); }
        return;
    }
    blk -= 1024;
    if (blk < 128) {  // dec_w3 (1024,64) -> [128,1024], pad rows n>=64 with 0
        int base = blk * 1024 + t;
#pragma unroll
        for (int i = 0; i < 4; i++) { int e = base + i * 256; int n = e >> 10, k = e & 1023;
            dw3t[e] = (n < AA) ? f2b(dec_w3[k * AA + n]) : f2b(0.0f); }
        return;
    }
    blk -= 128;
    {   // cnorm: one thread per codebook row
        int row = blk * 256 + t;
        float s = 0.f;
        for (int d = 0; d < DD; d++) { float v = codebook[row * DD + d]; s += v * v; }
        cnorm[row] = s;
    }
}

// ---------------------------------------------------------------------------
// GEMM: C[M,N] = A[M,K] * Bt[N,K]^T.  128x128 tile, 4 waves (2x2 of 64x64),
// 16x16x32 bf16 MFMA, BK=32, DOUBLE-BUFFERED LDS: one barrier per K-iter,
// next tile's global_load_lds issued right after the barrier so its latency
// is hidden under this tile's compute.  Pair-XOR swizzle (pos = q ^ ((row>>1)&3),
// 64 B rows) keeps ds_read_b128 conflict-free while preserving the
// wave-uniform-base + lane*16 contiguity global_load_lds requires.
// EPI: 0 = bias+relu -> bf16 C     1 = bias -> bf16 C
//      2 = VQ argmin (cnorm - 2*dot -> u64 atomicMin keys)
//      3 = bias+tanh, SSE vs action -> partials[64+..] (no store)
// ---------------------------------------------------------------------------
template <int N, int K, int EPI>
__global__ __launch_bounds__(256) void gemm_bt(
    const bf16* __restrict__ A, const bf16* __restrict__ Bt,
    const float* __restrict__ bias, bf16* __restrict__ C,
    const float* __restrict__ cnorm, u64* __restrict__ keys,
    const float* __restrict__ actionf, float* __restrict__ partials)
{
    __shared__ __align__(16) bf16 sA[2][128 * 32];   // 2 x 8 KB
    __shared__ __align__(16) bf16 sB[2][128 * 32];   // 2 x 8 KB
    const int t = threadIdx.x;
    const int wave = t >> 6, lane = t & 63;
    const int quad = lane >> 4, l16 = lane & 15;
    const int wm = (wave >> 1) << 6, wn = (wave & 1) << 6;
    const long tile_m = (long)blockIdx.y << 7;
    const int tile_n = blockIdx.x << 7;

    // Staging geometry: chunk c = p*256 + t (p=0,1) -> LDS byte c*16.
    // LDS position (row = c>>2, q' = c&3) holds global chunk q = q' ^ ((row>>1)&3).
    const int r0 = t >> 2;                                 // 0..63 (p adds 64)
    const int ko = (((t & 3) ^ ((t >> 3) & 3)) << 3);      // same for both p
    const bf16* ga0 = A + (tile_m + r0) * K + ko;
    const bf16* ga1 = ga0 + (long)64 * K;
    const bf16* gb0 = Bt + (long)(tile_n + r0) * K + ko;
    const bf16* gb1 = gb0 + (long)64 * K;

    const int ldsoff = (wave * 64) * 16;   // + p*256*16

    f32x4 acc[4][4];
#pragma unroll
    for (int i = 0; i < 4; i++)
#pragma unroll
        for (int j = 0; j < 4; j++) acc[i][j] = (f32x4){0.f, 0.f, 0.f, 0.f};

    constexpr int NIT = K / 32;

    auto stage = [&](int buf, int kk) {
        char* baseA = (char*)&sA[buf][0] + ldsoff;
        char* baseB = (char*)&sB[buf][0] + ldsoff;
        __builtin_amdgcn_global_load_lds((const __attribute__((address_space(1))) unsigned int*)(ga0 + kk),
                                         (__attribute__((address_space(3))) unsigned int*)baseA, 16, 0, 0);
        __builtin_amdgcn_global_load_lds((const __attribute__((address_space(1))) unsigned int*)(ga1 + kk),
                                         (__attribute__((address_space(3))) unsigned int*)(baseA + 4096), 16, 0, 0);
        __builtin_amdgcn_global_load_lds((const __attribute__((address_space(1))) unsigned int*)(gb0 + kk),
                                         (__attribute__((address_space(3))) unsigned int*)baseB, 16, 0, 0);
        __builtin_amdgcn_global_load_lds((const __attribute__((address_space(1))) unsigned int*)(gb1 + kk),
                                         (__attribute__((address_space(3))) unsigned int*)(baseB + 4096), 16, 0, 0);
    };

    stage(0, 0);

    for (int it = 0; it < NIT; ++it) {
        __syncthreads();                    // drains tile-it loads (vmcnt(0))
        if (it + 1 < NIT) stage((it + 1) & 1, (it + 1) * 32);
        const bf16* cA = &sA[it & 1][0];
        const bf16* cB = &sB[it & 1][0];
        bf16x8 af[4], bfr[4];
#pragma unroll
        for (int i = 0; i < 4; i++) {
            int ra = wm + i * 16 + l16;
            int pa = quad ^ ((ra >> 1) & 3);
            af[i] = *(const bf16x8*)&cA[ra * 32 + pa * 8];
            int rb = wn + i * 16 + l16;
            int pb = quad ^ ((rb >> 1) & 3);
            bfr[i] = *(const bf16x8*)&cB[rb * 32 + pb * 8];
        }
#pragma unroll
        for (int i = 0; i < 4; i++)
#pragma unroll
            for (int j = 0; j < 4; j++)
                acc[i][j] = __builtin_amdgcn_mfma_f32_16x16x32_bf16(af[i], bfr[j], acc[i][j], 0, 0, 0);
        // no trailing barrier: next iteration's loop-top barrier protects buf reuse
    }

    // C/D layout: col = lane&15, row = quad*4 + reg
    if (EPI == 0 || EPI == 1) {
#pragma unroll
        for (int i = 0; i < 4; i++) {
            int row = (int)tile_m + wm + i * 16 + (quad << 2);
#pragma unroll
            for (int j = 0; j < 4; j++) {
                int col = tile_n + wn + j * 16 + l16;
                float bv = bias[col];
#pragma unroll
                for (int r = 0; r < 4; r++) {
                    float v = acc[i][j][r] + bv;
                    if (EPI == 0) v = fmaxf(v, 0.f);
                    bf16 b = f2b(v);
                    int mine = (int)*(unsigned short*)&b;
                    int oth = __shfl_xor(mine, 1);
                    if (!(l16 & 1)) {
                        unsigned packed = (unsigned)mine | ((unsigned)oth << 16);
                        *(unsigned*)((char*)C + ((long)(row + r) * N + col) * 2) = packed;
                    }
                }
            }
        }
    } else if (EPI == 2) {
#pragma unroll
        for (int i = 0; i < 4; i++) {
#pragma unroll
            for (int r = 0; r < 4; r++) {
                float best = 3.4e38f; int bi = 0;
#pragma unroll
                for (int j = 0; j < 4; j++) {
                    int col = tile_n + wn + j * 16 + l16;
                    float v = __builtin_fmaf(-2.f, acc[i][j][r], cnorm[col]);
                    if (v < best || (v == best && col < bi)) { best = v; bi = col; }
                }
#pragma unroll
                for (int off = 1; off < 16; off <<= 1) {
                    float ov = __shfl_xor(best, off);
                    int   oi = __shfl_xor(bi, off);
                    if (ov < best || (ov == best && oi < bi)) { best = ov; bi = oi; }
                }
                if (l16 == 0) {
                    int row = (int)tile_m + wm + i * 16 + (quad << 2) + r;
                    u64 key = ((u64)f2ord(best) << 32) | (unsigned)bi;
                    atomicMin(&keys[row], key);
                }
            }
        }
    } else {  // EPI == 3: tanh + SSE vs action (cols >= AA are zero-padded)
        float ls = 0.f;
#pragma unroll
        for (int i = 0; i < 4; i++) {
            int row = (int)tile_m + wm + i * 16 + (quad << 2);
#pragma unroll
            for (int j = 0; j < 4; j++) {
                int col = tile_n + wn + j * 16 + l16;
                if (col < AA) {
                    float bv = bias[col];
#pragma unroll
                    for (int r = 0; r < 4; r++) {
                        float v = tanhf(acc[i][j][r] + bv);
                        float d = v - actionf[(long)(row + r) * AA + col];
                        ls += d * d;
                    }
                }
            }
        }
#pragma unroll
        for (int off = 32; off; off >>= 1) ls += __shfl_down(ls, off);
        __shared__ float wsum[4];
        if (lane == 0) wsum[wave] = ls;
        __syncthreads();
        if (t == 0) atomicAdd(&partials[64 + (blockIdx.y & 63)], wsum[0] + wsum[1] + wsum[2] + wsum[3]);
    }
}

// ---------------------------------------------------------------------------
// Gather q = codebook[idx] (bf16) and accumulate SSE(q - enc) -> partials[0..63]
// ---------------------------------------------------------------------------
__global__ void gather_vq(const u64* __restrict__ keys, const bf16* __restrict__ cb,
                          const bf16* __restrict__ enc, bf16* __restrict__ q,
                          float* __restrict__ partials)
{
    const int t = threadIdx.x;
    const int base = blockIdx.x * 4096;
    float s = 0.f;
#pragma unroll
    for (int e = 0; e < 16; e++) {
        int idx = base + e * 256 + t;
        int b = idx >> 8;
        int d = idx & 255;
        int code = (int)(keys[b] & 0xFFFFFFFFull);
        bf16 qv = cb[code * DD + d];
        q[idx] = qv;
        float df = b2f(qv) - b2f(enc[idx]);
        s += df * df;
    }
#pragma unroll
    for (int off = 32; off; off >>= 1) s += __shfl_down(s, off);
    __shared__ float wsum[4];
    int wave = t >> 6, lane = t & 63;
    if (lane == 0) wsum[wave] = s;
    __syncthreads();
    if (t == 0) atomicAdd(&partials[blockIdx.x & 63], wsum[0] + wsum[1] + wsum[2] + wsum[3]);
}

__global__ void finalize_kernel(const float* __restrict__ partials, float* __restrict__ out)
{
    int t = threadIdx.x;  // 64 threads
    float v = partials[t];
    float r = partials[64 + t];
#pragma unroll
    for (int off = 32; off; off >>= 1) { v += __shfl_down(v, off); r += __shfl_down(r, off); }
    if (t == 0) {
        float m = v * (1.f / ((float)BB * (float)DD));   // commitment == embedding (fwd)
        float vql = 1.25f * m;                           // 0.25*m + m
        float rl = r * (1.f / ((float)BB * (float)AA));
        out[0] = rl + vql;
        out[1] = rl;
        out[2] = vql;
        out[3] = m;
        out[4] = m;
    }
}

extern "C" void kernel_launch(void* const* d_in, const int* in_sizes, int n_in,
                              void* d_out, int out_size, void* d_ws, size_t ws_size,
                              hipStream_t stream)
{
    (void)in_sizes; (void)n_in; (void)out_size; (void)ws_size;
    const float* action   = (const float*)d_in[0];
    const float* enc_w1   = (const float*)d_in[1];
    const float* enc_b1   = (const float*)d_in[2];
    const float* enc_w2   = (const float*)d_in[3];
    const float* enc_b2   = (const float*)d_in[4];
    const float* mu_w     = (const float*)d_in[5];
    const float* mu_b     = (const float*)d_in[6];
    const float* codebook = (const float*)d_in[7];
    const float* dec_w1   = (const float*)d_in[8];
    const float* dec_b1   = (const float*)d_in[9];
    const float* dec_w2   = (const float*)d_in[10];
    const float* dec_b2   = (const float*)d_in[11];
    const float* dec_w3   = (const float*)d_in[12];
    const float* dec_b3   = (const float*)d_in[13];

    char* ws = (char*)d_ws;
    size_t off = 0;
    auto alloc = [&](size_t bytes) { char* p = ws + off; off += (bytes + 255) & ~(size_t)255; return p; };
    bf16* action_bf = (bf16*)alloc((size_t)BB * AA * 2);   // 4 MB
    bf16* ew1t      = (bf16*)alloc((size_t)HH * AA * 2);   // 128 KB
    bf16* ew2t      = (bf16*)alloc((size_t)HH * HH * 2);   // 2 MB
    bf16* muwt      = (bf16*)alloc((size_t)DD * HH * 2);   // 512 KB
    bf16* cbb       = (bf16*)alloc((size_t)KK * DD * 2);   // 2 MB
    bf16* dw1t      = (bf16*)alloc((size_t)HH * DD * 2);   // 512 KB
    bf16* dw2t      = (bf16*)alloc((size_t)HH * HH * 2);   // 2 MB
    bf16* dw3t      = (bf16*)alloc((size_t)128 * HH * 2);  // 256 KB
    float* cnorm    = (float*)alloc((size_t)KK * 4);
    u64* keys       = (u64*)alloc((size_t)BB * 8);         // 256 KB
    float* partials = (float*)alloc(128 * 4);
    bf16* h1        = (bf16*)alloc((size_t)BB * HH * 2);   // 64 MB
    bf16* h2        = (bf16*)alloc((size_t)BB * HH * 2);   // 64 MB
    bf16* encb      = (bf16*)alloc((size_t)BB * DD * 2);   // 16 MB
    bf16* qb        = (bf16*)alloc((size_t)BB * DD * 2);   // 16 MB

    hipMemsetAsync(keys, 0xFF, (size_t)BB * 8, stream);
    hipMemsetAsync(partials, 0, 128 * 4, stream);

    prep_kernel<<<5840, 256, 0, stream>>>(action, enc_w1, enc_w2, mu_w, codebook,
                                          dec_w1, dec_w2, dec_w3,
                                          action_bf, ew1t, ew2t, muwt, cbb, dw1t, dw2t, dw3t, cnorm);

    // encoder
    gemm_bt<HH, AA, 0><<<dim3(HH / 128, BB / 128), 256, 0, stream>>>(action_bf, ew1t, enc_b1, h1,
                                                                     nullptr, nullptr, nullptr, nullptr);
    gemm_bt<HH, HH, 0><<<dim3(HH / 128, BB / 128), 256, 0, stream>>>(h1, ew2t, enc_b2, h2,
                                                                     nullptr, nullptr, nullptr, nullptr);
    gemm_bt<DD, HH, 1><<<dim3(DD / 128, BB / 128), 256, 0, stream>>>(h2, muwt, mu_b, encb,
                                                                     nullptr, nullptr, nullptr, nullptr);
    // VQ: argmin over codebook of cnorm[k] - 2*enc.c_k
    gemm_bt<KK, DD, 2><<<dim3(KK / 128, BB / 128), 256, 0, stream>>>(encb, cbb, nullptr, nullptr,
                                                                     cnorm, keys, nullptr, nullptr);
    gather_vq<<<(BB * DD) / 4096, 256, 0, stream>>>(keys, cbb, encb, qb, partials);
    // decoder
    gemm_bt<HH, DD, 0><<<dim3(HH / 128, BB / 128), 256, 0, stream>>>(qb, dw1t, dec_b1, h1,
                                                                     nullptr, nullptr, nullptr, nullptr);
    gemm_bt<HH, HH, 0><<<dim3(HH / 128, BB / 128), 256, 0, stream>>>(h1, dw2t, dec_b2, h2,
                                                                     nullptr, nullptr, nullptr, nullptr);
    gemm_bt<128, HH, 3><<<dim3(1, BB / 128), 256, 0, stream>>>(h2, dw3t, dec_b3, nullptr,
                                                               nullptr, nullptr, action, partials);

    finalize_kernel<<<1, 64, 0, stream>>>(partials, (float*)d_out);
}

// Round 4
// 593.908 us; speedup vs baseline: 1.1814x; 1.1814x over previous
//
#include <hip/hip_runtime.h>
#include <hip/hip_bf16.h>

#define BB 32768
#define AA 64
#define HH 1024
#define DD 256
#define KK 4096

typedef __hip_bfloat16 bf16;
typedef __attribute__((ext_vector_type(8))) short bf16x8;
typedef __attribute__((ext_vector_type(4))) float f32x4;
typedef unsigned long long u64;

__device__ __forceinline__ float b2f(bf16 x) { return __bfloat162float(x); }
__device__ __forceinline__ bf16 f2b(float x) { return __float2bfloat16(x); }
__device__ __forceinline__ unsigned f2ord(float f) {
    unsigned u = __float_as_uint(f);
    return (u & 0x80000000u) ? ~u : (u | 0x80000000u);
}

// ---------------------------------------------------------------------------
// Prep: convert action to bf16; convert+transpose all weights to bf16 [N,K];
// codebook bf16 (already [N,K]); codebook row norms (wave-per-row).
// ---------------------------------------------------------------------------
__global__ void prep_kernel(const float* __restrict__ action,
                            const float* __restrict__ enc_w1,
                            const float* __restrict__ enc_w2,
                            const float* __restrict__ mu_w,
                            const float* __restrict__ codebook,
                            const float* __restrict__ dec_w1,
                            const float* __restrict__ dec_w2,
                            const float* __restrict__ dec_w3,
                            bf16* __restrict__ action_bf, bf16* __restrict__ ew1t,
                            bf16* __restrict__ ew2t, bf16* __restrict__ muwt,
                            bf16* __restrict__ cbb, bf16* __restrict__ dw1t,
                            bf16* __restrict__ dw2t, bf16* __restrict__ dw3t,
                            float* __restrict__ cnorm)
{
    int blk = blockIdx.x;
    const int t = threadIdx.x;
    if (blk < 2048) {
        int base = blk * 1024 + t;
#pragma unroll
        for (int i = 0; i < 4; i++) { int e = base + i * 256; action_bf[e] = f2b(action[e]); }
        return;
    }
    blk -= 2048;
    if (blk < 64) {  // enc_w1 (64,1024) -> [1024,64]
        int base = blk * 1024 + t;
#pragma unroll
        for (int i = 0; i < 4; i++) { int e = base + i * 256; int n = e >> 6, k = e & 63;
            ew1t[e] = f2b(enc_w1[k * HH + n]); }
        return;
    }
    blk -= 64;
    if (blk < 1024) {  // enc_w2 (1024,1024) -> T
        int base = blk * 1024 + t;
#pragma unroll
        for (int i = 0; i < 4; i++) { int e = base + i * 256; int n = e >> 10, k = e & 1023;
            ew2t[e] = f2b(enc_w2[k * HH + n]); }
        return;
    }
    blk -= 1024;
    if (blk < 256) {  // mu_w (1024,256) -> [256,1024]
        int base = blk * 1024 + t;
#pragma unroll
        for (int i = 0; i < 4; i++) { int e = base + i * 256; int n = e >> 10, k = e & 1023;
            muwt[e] = f2b(mu_w[k * DD + n]); }
        return;
    }
    blk -= 256;
    if (blk < 1024) {  // codebook convert (no transpose)
        int base = blk * 1024 + t;
#pragma unroll
        for (int i = 0; i < 4; i++) { int e = base + i * 256; cbb[e] = f2b(codebook[e]); }
        return;
    }
    blk -= 1024;
    if (blk < 256) {  // dec_w1 (256,1024) -> [1024,256]
        int base = blk * 1024 + t;
#pragma unroll
        for (int i = 0; i < 4; i++) { int e = base + i * 256; int n = e >> 8, k = e & 255;
            dw1t[e] = f2b(dec_w1[k * HH + n]); }
        return;
    }
    blk -= 256;
    if (blk < 1024) {  // dec_w2 (1024,1024) -> T
        int base = blk * 1024 + t;
#pragma unroll
        for (int i = 0; i < 4; i++) { int e = base + i * 256; int n = e >> 10, k = e & 1023;
            dw2t[e] = f2b(dec_w2[k * HH + n]); }
        return;
    }
    blk -= 1024;
    if (blk < 128) {  // dec_w3 (1024,64) -> [128,1024], pad rows n>=64 with 0
        int base = blk * 1024 + t;
#pragma unroll
        for (int i = 0; i < 4; i++) { int e = base + i * 256; int n = e >> 10, k = e & 1023;
            dw3t[e] = (n < AA) ? f2b(dec_w3[k * AA + n]) : f2b(0.0f); }
        return;
    }
    blk -= 128;
    {   // cnorm: 4 rows per block, one wave per row, float4 lane loads
        int wave = t >> 6, lane = t & 63;
        int row = blk * 4 + wave;
        const float4* cr = (const float4*)(codebook + (long)row * DD);
        float4 v = cr[lane];
        float s = v.x * v.x + v.y * v.y + v.z * v.z + v.w * v.w;
#pragma unroll
        for (int off = 32; off; off >>= 1) s += __shfl_down(s, off);
        if (lane == 0) cnorm[row] = s;
    }
}

// ---------------------------------------------------------------------------
// GEMM: C[M,N] = A[M,K] * Bt[N,K]^T.  128x128 tile, 4 waves (2x2 of 64x64),
// 16x16x32 bf16 MFMA, BK=64, single-buffered LDS (R1 structure — best so far),
// XOR-swizzled rows (conflict-free ds_read_b128), global_load_lds width-16.
// Register-diet version: __launch_bounds__(256,4) targets 4 blocks/CU
// (unified VGPR+AGPR <= 128).  B-fragments are loaded one at a time (4 live
// regs, not 16); staging addresses are uniform-base + one shared lane offset.
// EPI: 0 = bias+relu -> bf16 C     1 = bias -> bf16 C
//      2 = VQ argmin (cnorm - 2*dot -> u64 atomicMin keys)
//      3 = bias+tanh, SSE vs action -> partials[64+..] (no store)
// ---------------------------------------------------------------------------
template <int N, int K, int EPI>
__global__ __launch_bounds__(256, 4) void gemm_bt(
    const bf16* __restrict__ A, const bf16* __restrict__ Bt,
    const float* __restrict__ bias, bf16* __restrict__ C,
    const float* __restrict__ cnorm, u64* __restrict__ keys,
    const float* __restrict__ actionf, float* __restrict__ partials)
{
    __shared__ __align__(16) bf16 sA[128 * 64];   // 16 KB, 128 B rows, swizzled
    __shared__ __align__(16) bf16 sB[128 * 64];   // 16 KB
    const int t = threadIdx.x;
    const int wave = t >> 6, lane = t & 63;
    const int quad = lane >> 4, l16 = lane & 15;
    const int wm = (wave >> 1) << 6, wn = (wave & 1) << 6;
    const long tile_m = (long)blockIdx.y << 7;
    const int tile_n = blockIdx.x << 7;

    // Staging: chunk c = q*256 + t (q=0..3) -> LDS byte c*16.
    // LDS position (row = c>>3, q' = c&7) holds global chunk q'^ (row&7).
    const int r0 = t >> 3;                              // 0..31 (q adds 32)
    const int ko = (((t & 7) ^ (r0 & 7)) << 3);         // element offset in row
    const int laneoff = r0 * K + ko;                    // shared across q (VGPR x1)

    f32x4 acc[4][4];
#pragma unroll
    for (int i = 0; i < 4; i++)
#pragma unroll
        for (int j = 0; j < 4; j++) acc[i][j] = (f32x4){0.f, 0.f, 0.f, 0.f};

    for (int k0 = 0; k0 < K; k0 += 64) {
#pragma unroll
        for (int q = 0; q < 4; q++) {
            const bf16* srcA = A + ((tile_m + q * 32) * K + k0) + laneoff;
            const bf16* srcB = Bt + (((long)tile_n + q * 32) * K + k0) + laneoff;
            char* la = (char*)sA + (q * 256 + wave * 64) * 16;
            char* lb = (char*)sB + (q * 256 + wave * 64) * 16;
            __builtin_amdgcn_global_load_lds((const __attribute__((address_space(1))) unsigned int*)srcA,
                                             (__attribute__((address_space(3))) unsigned int*)la, 16, 0, 0);
            __builtin_amdgcn_global_load_lds((const __attribute__((address_space(1))) unsigned int*)srcB,
                                             (__attribute__((address_space(3))) unsigned int*)lb, 16, 0, 0);
        }
        __syncthreads();
#pragma unroll
        for (int ks = 0; ks < 2; ks++) {
            bf16x8 af[4];
#pragma unroll
            for (int i = 0; i < 4; i++) {
                int ra = wm + i * 16 + l16;
                int qa = ((ks << 2) | quad) ^ (l16 & 7);
                af[i] = *(const bf16x8*)&sA[ra * 64 + qa * 8];
            }
#pragma unroll
            for (int j = 0; j < 4; j++) {
                int rb = wn + j * 16 + l16;
                int qb = ((ks << 2) | quad) ^ (l16 & 7);
                bf16x8 bfr = *(const bf16x8*)&sB[rb * 64 + qb * 8];
#pragma unroll
                for (int i = 0; i < 4; i++)
                    acc[i][j] = __builtin_amdgcn_mfma_f32_16x16x32_bf16(af[i], bfr, acc[i][j], 0, 0, 0);
            }
        }
        __syncthreads();
    }

    // C/D layout: col = lane&15, row = quad*4 + reg
    if (EPI == 0 || EPI == 1) {
#pragma unroll
        for (int i = 0; i < 4; i++) {
            int row = (int)tile_m + wm + i * 16 + (quad << 2);
#pragma unroll
            for (int j = 0; j < 4; j++) {
                int col = tile_n + wn + j * 16 + l16;
                float bv = bias[col];
#pragma unroll
                for (int r = 0; r < 4; r++) {
                    float v = acc[i][j][r] + bv;
                    if (EPI == 0) v = fmaxf(v, 0.f);
                    bf16 b = f2b(v);
                    int mine = (int)*(unsigned short*)&b;
                    int oth = __shfl_xor(mine, 1);
                    if (!(l16 & 1)) {
                        unsigned packed = (unsigned)mine | ((unsigned)oth << 16);
                        *(unsigned*)((char*)C + ((long)(row + r) * N + col) * 2) = packed;
                    }
                }
            }
        }
    } else if (EPI == 2) {
#pragma unroll
        for (int i = 0; i < 4; i++) {
#pragma unroll
            for (int r = 0; r < 4; r++) {
                float best = 3.4e38f; int bi = 0;
#pragma unroll
                for (int j = 0; j < 4; j++) {
                    int col = tile_n + wn + j * 16 + l16;
                    float v = __builtin_fmaf(-2.f, acc[i][j][r], cnorm[col]);
                    if (v < best || (v == best && col < bi)) { best = v; bi = col; }
                }
#pragma unroll
                for (int off = 1; off < 16; off <<= 1) {
                    float ov = __shfl_xor(best, off);
                    int   oi = __shfl_xor(bi, off);
                    if (ov < best || (ov == best && oi < bi)) { best = ov; bi = oi; }
                }
                if (l16 == 0) {
                    int row = (int)tile_m + wm + i * 16 + (quad << 2) + r;
                    u64 key = ((u64)f2ord(best) << 32) | (unsigned)bi;
                    atomicMin(&keys[row], key);
                }
            }
        }
    } else {  // EPI == 3: tanh + SSE vs action (cols >= AA are zero-padded)
        float ls = 0.f;
#pragma unroll
        for (int i = 0; i < 4; i++) {
            int row = (int)tile_m + wm + i * 16 + (quad << 2);
#pragma unroll
            for (int j = 0; j < 4; j++) {
                int col = tile_n + wn + j * 16 + l16;
                if (col < AA) {
                    float bv = bias[col];
#pragma unroll
                    for (int r = 0; r < 4; r++) {
                        float v = tanhf(acc[i][j][r] + bv);
                        float d = v - actionf[(long)(row + r) * AA + col];
                        ls += d * d;
                    }
                }
            }
        }
#pragma unroll
        for (int off = 32; off; off >>= 1) ls += __shfl_down(ls, off);
        __shared__ float wsum[4];
        if (lane == 0) wsum[wave] = ls;
        __syncthreads();
        if (t == 0) atomicAdd(&partials[64 + (blockIdx.y & 63)], wsum[0] + wsum[1] + wsum[2] + wsum[3]);
    }
}

// ---------------------------------------------------------------------------
// Gather q = codebook[idx] (bf16) and accumulate SSE(q - enc) -> partials[0..63]
// ---------------------------------------------------------------------------
__global__ void gather_vq(const u64* __restrict__ keys, const bf16* __restrict__ cb,
                          const bf16* __restrict__ enc, bf16* __restrict__ q,
                          float* __restrict__ partials)
{
    const int t = threadIdx.x;
    const int base = blockIdx.x * 4096;
    float s = 0.f;
#pragma unroll
    for (int e = 0; e < 16; e++) {
        int idx = base + e * 256 + t;
        int b = idx >> 8;
        int d = idx & 255;
        int code = (int)(keys[b] & 0xFFFFFFFFull);
        bf16 qv = cb[code * DD + d];
        q[idx] = qv;
        float df = b2f(qv) - b2f(enc[idx]);
        s += df * df;
    }
#pragma unroll
    for (int off = 32; off; off >>= 1) s += __shfl_down(s, off);
    __shared__ float wsum[4];
    int wave = t >> 6, lane = t & 63;
    if (lane == 0) wsum[wave] = s;
    __syncthreads();
    if (t == 0) atomicAdd(&partials[blockIdx.x & 63], wsum[0] + wsum[1] + wsum[2] + wsum[3]);
}

__global__ void finalize_kernel(const float* __restrict__ partials, float* __restrict__ out)
{
    int t = threadIdx.x;  // 64 threads
    float v = partials[t];
    float r = partials[64 + t];
#pragma unroll
    for (int off = 32; off; off >>= 1) { v += __shfl_down(v, off); r += __shfl_down(r, off); }
    if (t == 0) {
        float m = v * (1.f / ((float)BB * (float)DD));   // commitment == embedding (fwd)
        float vql = 1.25f * m;                           // 0.25*m + m
        float rl = r * (1.f / ((float)BB * (float)AA));
        out[0] = rl + vql;
        out[1] = rl;
        out[2] = vql;
        out[3] = m;
        out[4] = m;
    }
}

extern "C" void kernel_launch(void* const* d_in, const int* in_sizes, int n_in,
                              void* d_out, int out_size, void* d_ws, size_t ws_size,
                              hipStream_t stream)
{
    (void)in_sizes; (void)n_in; (void)out_size; (void)ws_size;
    const float* action   = (const float*)d_in[0];
    const float* enc_w1   = (const float*)d_in[1];
    const float* enc_b1   = (const float*)d_in[2];
    const float* enc_w2   = (const float*)d_in[3];
    const float* enc_b2   = (const float*)d_in[4];
    const float* mu_w     = (const float*)d_in[5];
    const float* mu_b     = (const float*)d_in[6];
    const float* codebook = (const float*)d_in[7];
    const float* dec_w1   = (const float*)d_in[8];
    const float* dec_b1   = (const float*)d_in[9];
    const float* dec_w2   = (const float*)d_in[10];
    const float* dec_b2   = (const float*)d_in[11];
    const float* dec_w3   = (const float*)d_in[12];
    const float* dec_b3   = (const float*)d_in[13];

    char* ws = (char*)d_ws;
    size_t off = 0;
    auto alloc = [&](size_t bytes) { char* p = ws + off; off += (bytes + 255) & ~(size_t)255; return p; };
    bf16* action_bf = (bf16*)alloc((size_t)BB * AA * 2);   // 4 MB
    bf16* ew1t      = (bf16*)alloc((size_t)HH * AA * 2);   // 128 KB
    bf16* ew2t      = (bf16*)alloc((size_t)HH * HH * 2);   // 2 MB
    bf16* muwt      = (bf16*)alloc((size_t)DD * HH * 2);   // 512 KB
    bf16* cbb       = (bf16*)alloc((size_t)KK * DD * 2);   // 2 MB
    bf16* dw1t      = (bf16*)alloc((size_t)HH * DD * 2);   // 512 KB
    bf16* dw2t      = (bf16*)alloc((size_t)HH * HH * 2);   // 2 MB
    bf16* dw3t      = (bf16*)alloc((size_t)128 * HH * 2);  // 256 KB
    float* cnorm    = (float*)alloc((size_t)KK * 4);
    u64* keys       = (u64*)alloc((size_t)BB * 8);         // 256 KB
    float* partials = (float*)alloc(128 * 4);
    bf16* h1        = (bf16*)alloc((size_t)BB * HH * 2);   // 64 MB
    bf16* h2        = (bf16*)alloc((size_t)BB * HH * 2);   // 64 MB
    bf16* encb      = (bf16*)alloc((size_t)BB * DD * 2);   // 16 MB
    bf16* qb        = (bf16*)alloc((size_t)BB * DD * 2);   // 16 MB

    hipMemsetAsync(keys, 0xFF, (size_t)BB * 8, stream);
    hipMemsetAsync(partials, 0, 128 * 4, stream);

    prep_kernel<<<6848, 256, 0, stream>>>(action, enc_w1, enc_w2, mu_w, codebook,
                                          dec_w1, dec_w2, dec_w3,
                                          action_bf, ew1t, ew2t, muwt, cbb, dw1t, dw2t, dw3t, cnorm);

    // encoder
    gemm_bt<HH, AA, 0><<<dim3(HH / 128, BB / 128), 256, 0, stream>>>(action_bf, ew1t, enc_b1, h1,
                                                                     nullptr, nullptr, nullptr, nullptr);
    gemm_bt<HH, HH, 0><<<dim3(HH / 128, BB / 128), 256, 0, stream>>>(h1, ew2t, enc_b2, h2,
                                                                     nullptr, nullptr, nullptr, nullptr);
    gemm_bt<DD, HH, 1><<<dim3(DD / 128, BB / 128), 256, 0, stream>>>(h2, muwt, mu_b, encb,
                                                                     nullptr, nullptr, nullptr, nullptr);
    // VQ: argmin over codebook of cnorm[k] - 2*enc.c_k
    gemm_bt<KK, DD, 2><<<dim3(KK / 128, BB / 128), 256, 0, stream>>>(encb, cbb, nullptr, nullptr,
                                                                     cnorm, keys, nullptr, nullptr);
    gather_vq<<<(BB * DD) / 4096, 256, 0, stream>>>(keys, cbb, encb, qb, partials);
    // decoder
    gemm_bt<HH, DD, 0><<<dim3(HH / 128, BB / 128), 256, 0, stream>>>(qb, dw1t, dec_b1, h1,
                                                                     nullptr, nullptr, nullptr, nullptr);
    gemm_bt<HH, HH, 0><<<dim3(HH / 128, BB / 128), 256, 0, stream>>>(h1, dw2t, dec_b2, h2,
                                                                     nullptr, nullptr, nullptr, nullptr);
    gemm_bt<128, HH, 3><<<dim3(1, BB / 128), 256, 0, stream>>>(h2, dw3t, dec_b3, nullptr,
                                                               nullptr, nullptr, action, partials);

    finalize_kernel<<<1, 64, 0, stream>>>(partials, (float*)d_out);
}

// Round 5
// 557.072 us; speedup vs baseline: 1.2595x; 1.0661x over previous
//
#include <hip/hip_runtime.h>
#include <hip/hip_bf16.h>
#include <hip/hip_fp8.h>

#define BB 32768
#define AA 64
#define HH 1024
#define DD 256
#define KK 4096

typedef __attribute__((ext_vector_type(4))) float f32x4;
typedef unsigned long long u64;
typedef unsigned char u8;

__device__ __forceinline__ u8 f2f8(float x) { __hip_fp8_e4m3 v(x); return (u8)v.__x; }
__device__ __forceinline__ float f8tof(u8 b) { __hip_fp8_e4m3 t; t.__x = (__hip_fp8_storage_t)b; return (float)t; }
__device__ __forceinline__ unsigned f2ord(float f) {
    unsigned u = __float_as_uint(f);
    return (u & 0x80000000u) ? ~u : (u | 0x80000000u);
}

// Scales (power-of-2, folded out in epilogues):
//  action x8, weights x64, relu/linear activations x16, codebook & q x1024.

// ---------------------------------------------------------------------------
// Prep: all operands -> fp8 e4m3, weights transposed to [N,K]; action padded
// K=64->128; dec_w3 padded N=64->128; codebook row norms fp32.
// Block map (256 thr, 1024 elem/blk): action 4096 | ew1t 128 | ew2t 1024 |
// muwt 256 | cb 1024 | dw1t 256 | dw2t 1024 | dw3t 128 | cnorm 1024  = 8960
// ---------------------------------------------------------------------------
__global__ void prep_kernel(const float* __restrict__ action,
                            const float* __restrict__ enc_w1,
                            const float* __restrict__ enc_w2,
                            const float* __restrict__ mu_w,
                            const float* __restrict__ codebook,
                            const float* __restrict__ dec_w1,
                            const float* __restrict__ dec_w2,
                            const float* __restrict__ dec_w3,
                            u8* __restrict__ af8, u8* __restrict__ ew1t,
                            u8* __restrict__ ew2t, u8* __restrict__ muwt,
                            u8* __restrict__ cbf8, u8* __restrict__ dw1t,
                            u8* __restrict__ dw2t, u8* __restrict__ dw3t,
                            float* __restrict__ cnorm)
{
    int blk = blockIdx.x;
    const int t = threadIdx.x;
    if (blk < 4096) {  // action [32768 x 64] -> fp8 [32768 x 128], x8, zero-pad
        int base = blk * 1024 + t;
#pragma unroll
        for (int i = 0; i < 4; i++) { int e = base + i * 256; int b = e >> 7, k = e & 127;
            af8[e] = f2f8(k < AA ? action[(b << 6) + k] * 8.f : 0.f); }
        return;
    }
    blk -= 4096;
    if (blk < 128) {  // enc_w1 (64,1024) -> [1024 x 128] x64, zero-pad K
        int base = blk * 1024 + t;
#pragma unroll
        for (int i = 0; i < 4; i++) { int e = base + i * 256; int n = e >> 7, k = e & 127;
            ew1t[e] = f2f8(k < AA ? enc_w1[k * HH + n] * 64.f : 0.f); }
        return;
    }
    blk -= 128;
    if (blk < 1024) {  // enc_w2 (1024,1024) -> T x64
        int base = blk * 1024 + t;
#pragma unroll
        for (int i = 0; i < 4; i++) { int e = base + i * 256; int n = e >> 10, k = e & 1023;
            ew2t[e] = f2f8(enc_w2[k * HH + n] * 64.f); }
        return;
    }
    blk -= 1024;
    if (blk < 256) {  // mu_w (1024,256) -> [256 x 1024] x64
        int base = blk * 1024 + t;
#pragma unroll
        for (int i = 0; i < 4; i++) { int e = base + i * 256; int n = e >> 10, k = e & 1023;
            muwt[e] = f2f8(mu_w[k * DD + n] * 64.f); }
        return;
    }
    blk -= 256;
    if (blk < 1024) {  // codebook [4096 x 256] x1024 (no transpose)
        int base = blk * 1024 + t;
#pragma unroll
        for (int i = 0; i < 4; i++) { int e = base + i * 256; cbf8[e] = f2f8(codebook[e] * 1024.f); }
        return;
    }
    blk -= 1024;
    if (blk < 256) {  // dec_w1 (256,1024) -> [1024 x 256] x64
        int base = blk * 1024 + t;
#pragma unroll
        for (int i = 0; i < 4; i++) { int e = base + i * 256; int n = e >> 8, k = e & 255;
            dw1t[e] = f2f8(dec_w1[k * HH + n] * 64.f); }
        return;
    }
    blk -= 256;
    if (blk < 1024) {  // dec_w2 (1024,1024) -> T x64
        int base = blk * 1024 + t;
#pragma unroll
        for (int i = 0; i < 4; i++) { int e = base + i * 256; int n = e >> 10, k = e & 1023;
            dw2t[e] = f2f8(dec_w2[k * HH + n] * 64.f); }
        return;
    }
    blk -= 1024;
    if (blk < 128) {  // dec_w3 (1024,64) -> [128 x 1024] x64, zero-pad N
        int base = blk * 1024 + t;
#pragma unroll
        for (int i = 0; i < 4; i++) { int e = base + i * 256; int n = e >> 10, k = e & 1023;
            dw3t[e] = f2f8(n < AA ? dec_w3[k * AA + n] * 64.f : 0.f); }
        return;
    }
    blk -= 128;
    {   // cnorm: 4 rows/block, wave per row, fp32 exact
        int wave = t >> 6, lane = t & 63;
        int row = blk * 4 + wave;
        const float4* cr = (const float4*)(codebook + (long)row * DD);
        float4 v = cr[lane];
        float s = v.x * v.x + v.y * v.y + v.z * v.z + v.w * v.w;
#pragma unroll
        for (int off = 32; off; off >>= 1) s += __shfl_down(s, off);
        if (lane == 0) cnorm[row] = s;
    }
}

// ---------------------------------------------------------------------------
// fp8 GEMM: C[M,N] = (A[M,K] * Bt[N,K]^T) * ds.  128x128 tile, 4 waves,
// 16x16x32 fp8_fp8 MFMA, BK=128 (fp8 -> same 32 KB LDS as bf16 BK=64, but
// HALF the K-iterations / barrier drains).  Rows are 128 B = 8 16B-chunks,
// XOR-swizzled (slot = chunk ^ (row&7)): global_load_lds stays lane-contig,
// ds_read_b64 fragment reads are <=2-way (free).
// EPI: 0 = relu(v+bias)*os -> fp8 C   1 = (v+bias)*os -> fp8 C
//      2 = VQ argmin (cnorm - 2v -> u64 atomicMin keys)
//      3 = tanh(v+bias), SSE vs fp32 action -> partials[64+..]
// ---------------------------------------------------------------------------
template <int N, int K, int EPI>
__global__ __launch_bounds__(256, 4) void gemm_f8(
    const u8* __restrict__ A, const u8* __restrict__ Bt,
    const float* __restrict__ bias, u8* __restrict__ C,
    float ds, float os,
    const float* __restrict__ cnorm, u64* __restrict__ keys,
    const float* __restrict__ actionf, float* __restrict__ partials)
{
    __shared__ __align__(16) u8 sA[128 * 128];   // 16 KB
    __shared__ __align__(16) u8 sB[128 * 128];   // 16 KB
    const int t = threadIdx.x;
    const int wave = t >> 6, lane = t & 63;
    const int quad = lane >> 4, l16 = lane & 15;
    const int wm = (wave >> 1) << 6, wn = (wave & 1) << 6;
    const long tile_m = (long)blockIdx.y << 7;
    const int tile_n = blockIdx.x << 7;

    // Stage: chunk c = q*256 + t -> LDS byte c*16; row = c>>3, slot = c&7
    // holds global chunk slot ^ (row&7).
    const int r0 = t >> 3;                               // 0..31 (q adds 32)
    const int ko = (((t & 7) ^ (r0 & 7)) << 4);          // byte offset in row
    const int laneoff = r0 * K + ko;

    f32x4 acc[4][4];
#pragma unroll
    for (int i = 0; i < 4; i++)
#pragma unroll
        for (int j = 0; j < 4; j++) acc[i][j] = (f32x4){0.f, 0.f, 0.f, 0.f};

    const int q8 = (quad & 1) << 3;      // byte-in-chunk for fragment reads
    const int qs = quad >> 1;            // chunk parity from quad

    for (int k0 = 0; k0 < K; k0 += 128) {
#pragma unroll
        for (int q = 0; q < 4; q++) {
            const u8* srcA = A + (tile_m + q * 32) * K + k0 + laneoff;
            const u8* srcB = Bt + ((long)tile_n + q * 32) * K + k0 + laneoff;
            char* la = (char*)sA + (q * 256 + wave * 64) * 16;
            char* lb = (char*)sB + (q * 256 + wave * 64) * 16;
            __builtin_amdgcn_global_load_lds((const __attribute__((address_space(1))) unsigned int*)srcA,
                                             (__attribute__((address_space(3))) unsigned int*)la, 16, 0, 0);
            __builtin_amdgcn_global_load_lds((const __attribute__((address_space(1))) unsigned int*)srcB,
                                             (__attribute__((address_space(3))) unsigned int*)lb, 16, 0, 0);
        }
        __syncthreads();
#pragma unroll
        for (int ks = 0; ks < 4; ks++) {
            const int slot = ((ks << 1) | qs) ^ (l16 & 7);   // same for A and B rows
            long af[4];
#pragma unroll
            for (int i = 0; i < 4; i++) {
                int ra = wm + i * 16 + l16;
                af[i] = *(const long*)&sA[ra * 128 + slot * 16 + q8];
            }
#pragma unroll
            for (int j = 0; j < 4; j++) {
                int rb = wn + j * 16 + l16;
                long bv = *(const long*)&sB[rb * 128 + slot * 16 + q8];
#pragma unroll
                for (int i = 0; i < 4; i++)
                    acc[i][j] = __builtin_amdgcn_mfma_f32_16x16x32_fp8_fp8(af[i], bv, acc[i][j], 0, 0, 0);
            }
        }
        __syncthreads();
    }

    // C/D layout: col = lane&15, row = quad*4 + reg
    if (EPI == 0 || EPI == 1) {
#pragma unroll
        for (int i = 0; i < 4; i++) {
            int row = (int)tile_m + wm + i * 16 + (quad << 2);
#pragma unroll
            for (int j = 0; j < 4; j++) {
                int col = tile_n + wn + j * 16 + l16;
                float bv = bias[col];
#pragma unroll
                for (int r = 0; r < 4; r++) {
                    float v = __builtin_fmaf(acc[i][j][r], ds, bv);
                    if (EPI == 0) v = fmaxf(v, 0.f);
                    int mine = (int)f2f8(v * os);
                    int oth = __shfl_xor(mine, 1);
                    if (!(l16 & 1)) {
                        unsigned short packed = (unsigned short)(mine | (oth << 8));
                        *(unsigned short*)(C + (long)(row + r) * N + col) = packed;
                    }
                }
            }
        }
    } else if (EPI == 2) {
#pragma unroll
        for (int i = 0; i < 4; i++) {
#pragma unroll
            for (int r = 0; r < 4; r++) {
                float best = 3.4e38f; int bi = 0;
#pragma unroll
                for (int j = 0; j < 4; j++) {
                    int col = tile_n + wn + j * 16 + l16;
                    float v = __builtin_fmaf(-2.f * ds, acc[i][j][r], cnorm[col]);
                    if (v < best || (v == best && col < bi)) { best = v; bi = col; }
                }
#pragma unroll
                for (int off = 1; off < 16; off <<= 1) {
                    float ov = __shfl_xor(best, off);
                    int   oi = __shfl_xor(bi, off);
                    if (ov < best || (ov == best && oi < bi)) { best = ov; bi = oi; }
                }
                if (l16 == 0) {
                    int row = (int)tile_m + wm + i * 16 + (quad << 2) + r;
                    u64 key = ((u64)f2ord(best) << 32) | (unsigned)bi;
                    atomicMin(&keys[row], key);
                }
            }
        }
    } else {  // EPI == 3: tanh + SSE vs fp32 action (cols >= AA zero-padded)
        float ls = 0.f;
#pragma unroll
        for (int i = 0; i < 4; i++) {
            int row = (int)tile_m + wm + i * 16 + (quad << 2);
#pragma unroll
            for (int j = 0; j < 4; j++) {
                int col = tile_n + wn + j * 16 + l16;
                if (col < AA) {
                    float bv = bias[col];
#pragma unroll
                    for (int r = 0; r < 4; r++) {
                        float v = tanhf(__builtin_fmaf(acc[i][j][r], ds, bv));
                        float d = v - actionf[(long)(row + r) * AA + col];
                        ls += d * d;
                    }
                }
            }
        }
#pragma unroll
        for (int off = 32; off; off >>= 1) ls += __shfl_down(ls, off);
        __shared__ float wsum[4];
        if (lane == 0) wsum[wave] = ls;
        __syncthreads();
        if (t == 0) atomicAdd(&partials[64 + (blockIdx.y & 63)], wsum[0] + wsum[1] + wsum[2] + wsum[3]);
    }
}

// ---------------------------------------------------------------------------
// Gather q = codebook[idx] (fp32 exact) -> qb fp8 x1024; SSE(q - enc) from
// fp8 enc (/16) -> partials[0..63]
// ---------------------------------------------------------------------------
__global__ void gather_vq(const u64* __restrict__ keys, const float* __restrict__ cb,
                          const u8* __restrict__ enc8, u8* __restrict__ q8,
                          float* __restrict__ partials)
{
    const int t = threadIdx.x;
    const int base = blockIdx.x * 4096;
    float s = 0.f;
#pragma unroll
    for (int e = 0; e < 16; e++) {
        int idx = base + e * 256 + t;
        int b = idx >> 8;
        int d = idx & 255;
        int code = (int)(keys[b] & 0xFFFFFFFFull);
        float qv = cb[code * DD + d];
        q8[idx] = f2f8(qv * 1024.f);
        float df = qv - f8tof(enc8[idx]) * 0.0625f;
        s += df * df;
    }
#pragma unroll
    for (int off = 32; off; off >>= 1) s += __shfl_down(s, off);
    __shared__ float wsum[4];
    int wave = t >> 6, lane = t & 63;
    if (lane == 0) wsum[wave] = s;
    __syncthreads();
    if (t == 0) atomicAdd(&partials[blockIdx.x & 63], wsum[0] + wsum[1] + wsum[2] + wsum[3]);
}

__global__ void finalize_kernel(const float* __restrict__ partials, float* __restrict__ out)
{
    int t = threadIdx.x;  // 64 threads
    float v = partials[t];
    float r = partials[64 + t];
#pragma unroll
    for (int off = 32; off; off >>= 1) { v += __shfl_down(v, off); r += __shfl_down(r, off); }
    if (t == 0) {
        float m = v * (1.f / ((float)BB * (float)DD));   // commitment == embedding (fwd)
        float vql = 1.25f * m;                           // 0.25*m + m
        float rl = r * (1.f / ((float)BB * (float)AA));
        out[0] = rl + vql;
        out[1] = rl;
        out[2] = vql;
        out[3] = m;
        out[4] = m;
    }
}

extern "C" void kernel_launch(void* const* d_in, const int* in_sizes, int n_in,
                              void* d_out, int out_size, void* d_ws, size_t ws_size,
                              hipStream_t stream)
{
    (void)in_sizes; (void)n_in; (void)out_size; (void)ws_size;
    const float* action   = (const float*)d_in[0];
    const float* enc_w1   = (const float*)d_in[1];
    const float* enc_b1   = (const float*)d_in[2];
    const float* enc_w2   = (const float*)d_in[3];
    const float* enc_b2   = (const float*)d_in[4];
    const float* mu_w     = (const float*)d_in[5];
    const float* mu_b     = (const float*)d_in[6];
    const float* codebook = (const float*)d_in[7];
    const float* dec_w1   = (const float*)d_in[8];
    const float* dec_b1   = (const float*)d_in[9];
    const float* dec_w2   = (const float*)d_in[10];
    const float* dec_b2   = (const float*)d_in[11];
    const float* dec_w3   = (const float*)d_in[12];
    const float* dec_b3   = (const float*)d_in[13];

    char* ws = (char*)d_ws;
    size_t off = 0;
    auto alloc = [&](size_t bytes) { char* p = ws + off; off += (bytes + 255) & ~(size_t)255; return p; };
    u8* af8      = (u8*)alloc((size_t)BB * 128);       // 4 MB (K padded 64->128)
    u8* ew1t     = (u8*)alloc((size_t)HH * 128);       // 128 KB
    u8* ew2t     = (u8*)alloc((size_t)HH * HH);        // 1 MB
    u8* muwt     = (u8*)alloc((size_t)DD * HH);        // 256 KB
    u8* cbf8     = (u8*)alloc((size_t)KK * DD);        // 1 MB
    u8* dw1t     = (u8*)alloc((size_t)HH * DD);        // 256 KB
    u8* dw2t     = (u8*)alloc((size_t)HH * HH);        // 1 MB
    u8* dw3t     = (u8*)alloc((size_t)128 * HH);       // 128 KB
    float* cnorm = (float*)alloc((size_t)KK * 4);
    u64* keys    = (u64*)alloc((size_t)BB * 8);        // 256 KB
    float* partials = (float*)alloc(128 * 4);
    u8* h1       = (u8*)alloc((size_t)BB * HH);        // 32 MB
    u8* h2       = (u8*)alloc((size_t)BB * HH);        // 32 MB
    u8* encb     = (u8*)alloc((size_t)BB * DD);        // 8 MB
    u8* qb       = (u8*)alloc((size_t)BB * DD);        // 8 MB

    hipMemsetAsync(keys, 0xFF, (size_t)BB * 8, stream);
    hipMemsetAsync(partials, 0, 128 * 4, stream);

    prep_kernel<<<8960, 256, 0, stream>>>(action, enc_w1, enc_w2, mu_w, codebook,
                                          dec_w1, dec_w2, dec_w3,
                                          af8, ew1t, ew2t, muwt, cbf8, dw1t, dw2t, dw3t, cnorm);

    // encoder  (ds = 1/(scaleA*scaleB), os = activation store scale)
    gemm_f8<HH, 128, 0><<<dim3(HH / 128, BB / 128), 256, 0, stream>>>(
        af8, ew1t, enc_b1, h1, 1.f / 512.f, 16.f, nullptr, nullptr, nullptr, nullptr);
    gemm_f8<HH, HH, 0><<<dim3(HH / 128, BB / 128), 256, 0, stream>>>(
        h1, ew2t, enc_b2, h2, 1.f / 1024.f, 16.f, nullptr, nullptr, nullptr, nullptr);
    gemm_f8<DD, HH, 1><<<dim3(DD / 128, BB / 128), 256, 0, stream>>>(
        h2, muwt, mu_b, encb, 1.f / 1024.f, 16.f, nullptr, nullptr, nullptr, nullptr);
    // VQ: argmin over codebook of cnorm[k] - 2*enc.c_k   (ds = 1/(16*1024))
    gemm_f8<KK, DD, 2><<<dim3(KK / 128, BB / 128), 256, 0, stream>>>(
        encb, cbf8, nullptr, nullptr, 1.f / 16384.f, 0.f, cnorm, keys, nullptr, nullptr);
    gather_vq<<<(BB * DD) / 4096, 256, 0, stream>>>(keys, codebook, encb, qb, partials);
    // decoder
    gemm_f8<HH, DD, 0><<<dim3(HH / 128, BB / 128), 256, 0, stream>>>(
        qb, dw1t, dec_b1, h1, 1.f / 65536.f, 16.f, nullptr, nullptr, nullptr, nullptr);
    gemm_f8<HH, HH, 0><<<dim3(HH / 128, BB / 128), 256, 0, stream>>>(
        h1, dw2t, dec_b2, h2, 1.f / 1024.f, 16.f, nullptr, nullptr, nullptr, nullptr);
    gemm_f8<128, HH, 3><<<dim3(1, BB / 128), 256, 0, stream>>>(
        h2, dw3t, dec_b3, nullptr, 1.f / 1024.f, 0.f, nullptr, nullptr, action, partials);

    finalize_kernel<<<1, 64, 0, stream>>>(partials, (float*)d_out);
}